// Round 3
// baseline (82311.047 us; speedup 1.0000x reference)
//
#include <hip/hip_runtime.h>

// CVRAE forward, persistent plain-launch version (grid=256=CU count).
// B=256, S=512, A=64, H=1024, Z=256.
// Balanced static work partition: 1024 waves; weights XCD-local in L2.

typedef float f32x4 __attribute__((ext_vector_type(4)));
typedef __bf16 bf16x8 __attribute__((ext_vector_type(8)));

#define BB 256
#define SS 512
#define HH 1024
#define ZZ 256
#define AA 64
#define NWG 256

__device__ __forceinline__ float softplus_(float x) {
    return (x > 15.f) ? x : log1pf(expf(x));
}
__device__ __forceinline__ float sigmoid_(float x) {
    return 1.f / (1.f + expf(-x));
}

// ---------------- device barrier ----------------
// Ring of 8 slots, monotone counters (never reset).
__device__ __forceinline__ void gbar(unsigned* bar, unsigned p, int wg) {
    __syncthreads();
    if (threadIdx.x == 0) {
        unsigned s = p & 7u;
        unsigned exp = (p >> 3) + 1u;
        unsigned* leaf = bar + (s * 8 + (wg >> 5)) * 16;
        unsigned* root = bar + (64 + s) * 16;
        unsigned* flag = bar + (72 + s) * 16;
        unsigned old = __hip_atomic_fetch_add(leaf, 1u, __ATOMIC_ACQ_REL, __HIP_MEMORY_SCOPE_AGENT);
        if (old == 32u * exp - 1u) {
            unsigned old2 = __hip_atomic_fetch_add(root, 1u, __ATOMIC_ACQ_REL, __HIP_MEMORY_SCOPE_AGENT);
            if (old2 == 8u * exp - 1u) {
                __hip_atomic_store(flag, exp, __ATOMIC_RELEASE, __HIP_MEMORY_SCOPE_AGENT);
            }
        }
        while (__hip_atomic_load(flag, __ATOMIC_ACQUIRE, __HIP_MEMORY_SCOPE_AGENT) < exp) {
            __builtin_amdgcn_s_sleep(1);
        }
    }
    __syncthreads();
}

// ---------------- wave GEMM helper (tail use) ----------------
template<int MT, int NT>
__device__ __forceinline__ void wgemm(const __bf16* __restrict__ A, int lda, int mstride,
                                      const __bf16* __restrict__ B, int ldb, int nstride,
                                      int K, f32x4 (&acc)[MT][NT]) {
    int lane = threadIdx.x & 63;
    int rr = lane & 15;
    int ko = (lane >> 4) * 8;
    const __bf16* ap = A + rr * lda + ko;
    const __bf16* bp = B + rr * ldb + ko;
    #pragma unroll 2
    for (int k = 0; k < K; k += 32) {
        bf16x8 af[MT], bfr[NT];
        #pragma unroll
        for (int mt = 0; mt < MT; mt++) af[mt] = *(const bf16x8*)(ap + mt * mstride + k);
        #pragma unroll
        for (int nt = 0; nt < NT; nt++) bfr[nt] = *(const bf16x8*)(bp + nt * nstride + k);
        #pragma unroll
        for (int mt = 0; mt < MT; mt++)
            #pragma unroll
            for (int nt = 0; nt < NT; nt++)
                acc[mt][nt] = __builtin_amdgcn_mfma_f32_16x16x32_bf16(af[mt], bfr[nt], acc[mt][nt], 0, 0, 0);
    }
}

// ---------------- prep kernels ----------------

__global__ void k_zerobar(unsigned* b) {
    for (int i = threadIdx.x; i < 1280; i += 256) b[i] = 0u;
}

__global__ void k_pack(const float* __restrict__ src, int src_ld, int col_off,
                       __bf16* __restrict__ dst, int cols, int total) {
    int i = blockIdx.x * 256 + threadIdx.x;
    if (i >= total) return;
    int r = i / cols, c = i - r * cols;
    dst[i] = (__bf16)src[r * src_ld + col_off + c];
}

__global__ void k_copyf(const float* __restrict__ s, float* __restrict__ d, int n) {
    int i = blockIdx.x * 256 + threadIdx.x;
    if (i < n) d[i] = s[i];
}

__global__ void k_px(const float* __restrict__ phi_x_w, const float* __restrict__ phi_x_b,
                     float* __restrict__ px) {
    int i = blockIdx.x * 256 + threadIdx.x;  // 64*1024
    int a = i >> 10, hh = i & 1023;
    px[i] = fmaxf(phi_x_w[hh * AA + a] + phi_x_b[hh], 0.f);
}

__global__ __launch_bounds__(256) void k_tables(const float* __restrict__ enc_w1,
                                                const float* __restrict__ wih,
                                                const float* __restrict__ px,
                                                float* __restrict__ encpx,
                                                float* __restrict__ gipx) {
    __shared__ float spx[64][65];
    int tid = threadIdx.x;
    int cg = blockIdx.x * 4 + (tid >> 6);
    int a = tid & 63;
    const float* wrow = (cg < 1024) ? (enc_w1 + cg * 2048) : (wih + (cg - 1024) * 2048);
    float sum = 0.f;
    for (int k0 = 0; k0 < 1024; k0 += 64) {
        __syncthreads();
        for (int e = tid; e < 4096; e += 256)
            spx[e >> 6][e & 63] = px[((e >> 6) << 10) + k0 + (e & 63)];
        __syncthreads();
        #pragma unroll 8
        for (int kk = 0; kk < 64; kk++) sum += wrow[k0 + kk] * spx[a][kk];
    }
    if (cg < 1024) encpx[a * 1024 + cg] = sum;
    else gipx[a * 3072 + (cg - 1024)] = sum;
}

// ---------------- persistent kernel ----------------

struct PArgs {
    const int* x; const float* eps;
    const __bf16 *WA, *W2, *WPZ, *WIH, *WHH, *WDEC, *WACT;
    const float *encpx, *gipx;
    const float *eb1, *pb1, *eb2, *pb2, *pzb, *decb, *actb, *bih, *bhh;
    float *hf0, *hf1; __bf16 *hb0, *hb1;
    __bf16 *hidcat, *zbuf, *pzbuf, *tailhid, *decbuf;
    float *gh; float *kldbuf; unsigned* bar;
    float* out;
};

__global__ __launch_bounds__(256) void k_persist(PArgs a) {
    int wg = blockIdx.x;
    int tid = threadIdx.x;
    int v = tid >> 6;                // wave in WG
    int gw = wg * 4 + v;             // global wave
    int lane = tid & 63;
    int rr = lane & 15;              // fragment row
    int ko = (lane >> 4) * 8;        // fragment k-offset
    int col = lane & 15, rq = (lane >> 4) * 4;
    unsigned p = 0;
    float kl = 0.f;
    float* hf[2] = {a.hf0, a.hf1};
    __bf16* hb[2] = {a.hb0, a.hb1};

    __shared__ float lds2[4][2][256];   // P2 K-split partials

    // static roles
    const int cg1 = wg & 63, mg1 = wg >> 6;       // P1: col-group (80 cols), m-group
    const int zsl = wg & 15, mt2 = wg >> 4;       // P2: z-slice, m-tile
    const int cg3 = wg & 63, mg3 = wg >> 6;       // P3
    const int js4 = wg & 63, mg4 = wg >> 6;       // P4: j-slice, m-group

    // P1 B pointers (fixed across steps)
    const __bf16* bp1[5];
    #pragma unroll
    for (int nt = 0; nt < 5; nt++) {
        int n = cg1 * 80 + nt * 16 + rr;
        bp1[nt] = ((n < 2048) ? (a.WA + (size_t)n * HH)
                              : (a.WHH + (size_t)(n - 2048) * HH)) + ko;
    }
    const __bf16* bp2e = a.W2 + (size_t)(zsl * 16 + rr) * HH + v * 256 + ko;
    const __bf16* bp2p = a.W2 + (size_t)(256 + zsl * 16 + rr) * HH + v * 256 + ko;
    const __bf16* bp3 = a.WPZ + (size_t)(cg3 * 16 + rr) * ZZ + ko;
    const __bf16* bp4[3];
    #pragma unroll
    for (int g = 0; g < 3; g++)
        bp4[g] = a.WIH + (size_t)(g * 1024 + js4 * 16 + rr) * HH + ko;

    for (int t = 0; t < SS; t++) {
        int cur = t & 1, nxt = cur ^ 1;

        // ---- P1: hidcat (cols 0..2047) + gh (cols 2048..5119) ----
        {
            int mt = mg1 * 4 + v;                 // m-tile [0,16)
            const __bf16* ap = hb[cur] + (size_t)(mt * 16 + rr) * HH + ko;
            f32x4 acc[5] = {};
            #pragma unroll 2
            for (int k = 0; k < HH; k += 32) {
                bf16x8 af = *(const bf16x8*)(ap + k);
                #pragma unroll
                for (int nt = 0; nt < 5; nt++)
                    acc[nt] = __builtin_amdgcn_mfma_f32_16x16x32_bf16(
                        af, *(const bf16x8*)(bp1[nt] + k), acc[nt], 0, 0, 0);
            }
            int xb[4];
            #pragma unroll
            for (int i = 0; i < 4; i++) xb[i] = a.x[(mt * 16 + rq + i) * SS + t];
            #pragma unroll
            for (int nt = 0; nt < 5; nt++) {
                int n = cg1 * 80 + nt * 16 + col;
                if (n < 1024) {
                    float bias = a.eb1[n];
                    #pragma unroll
                    for (int i = 0; i < 4; i++) {
                        int m = mt * 16 + rq + i;
                        float val = acc[nt][i] + bias + a.encpx[xb[i] * 1024 + n];
                        a.hidcat[m * 2048 + n] = (__bf16)fmaxf(val, 0.f);
                    }
                } else if (n < 2048) {
                    float bias = a.pb1[n - 1024];
                    #pragma unroll
                    for (int i = 0; i < 4; i++) {
                        int m = mt * 16 + rq + i;
                        a.hidcat[m * 2048 + n] = (__bf16)fmaxf(acc[nt][i] + bias, 0.f);
                    }
                } else {
                    int gc = n - 2048;
                    #pragma unroll
                    for (int i = 0; i < 4; i++) {
                        int m = mt * 16 + rq + i;
                        a.gh[m * 3072 + gc] = acc[nt][i];
                    }
                }
            }
        }
        gbar(a.bar, p++, wg);

        // ---- P2: enc/pri logits (K split over 4 waves), kld, z sample ----
        {
            const __bf16* ae_p = a.hidcat + (size_t)(mt2 * 16 + rr) * 2048 + v * 256 + ko;
            const __bf16* ap_p = ae_p + 1024;
            f32x4 ae = {0.f,0.f,0.f,0.f}, av = {0.f,0.f,0.f,0.f};
            #pragma unroll
            for (int k = 0; k < 256; k += 32) {
                ae = __builtin_amdgcn_mfma_f32_16x16x32_bf16(
                    *(const bf16x8*)(ae_p + k), *(const bf16x8*)(bp2e + k), ae, 0, 0, 0);
                av = __builtin_amdgcn_mfma_f32_16x16x32_bf16(
                    *(const bf16x8*)(ap_p + k), *(const bf16x8*)(bp2p + k), av, 0, 0, 0);
            }
            #pragma unroll
            for (int i = 0; i < 4; i++) {
                int idx = (rq + i) * 16 + col;
                lds2[v][0][idx] = ae[i];
                lds2[v][1][idx] = av[i];
            }
            __syncthreads();
            {
                float e = lds2[0][0][tid] + lds2[1][0][tid] + lds2[2][0][tid] + lds2[3][0][tid];
                float pv = lds2[0][1][tid] + lds2[1][1][tid] + lds2[2][1][tid] + lds2[3][1][tid];
                int m = mt2 * 16 + (tid >> 4);
                int z = zsl * 16 + (tid & 15);
                float enc = e + a.eb2[z];
                float pri = pv + a.pb2[z];
                float es = softplus_(enc), ps = softplus_(pri);
                float d = enc - pri;
                kl += 2.f * (logf(ps) - logf(es)) + (es * es + d * d) / (ps * ps) - 1.f;
                const float* epst = a.eps + (size_t)t * BB * ZZ;
                a.zbuf[m * ZZ + z] = (__bf16)(epst[m * ZZ + z] * es + enc);
            }
        }
        gbar(a.bar, p++, wg);

        // ---- P3: pz = relu(z @ phi_z_w^T + b) ----
        {
            int mt = mg3 * 4 + v;
            const __bf16* ap = a.zbuf + (size_t)(mt * 16 + rr) * ZZ + ko;
            f32x4 acc = {0.f,0.f,0.f,0.f};
            #pragma unroll
            for (int k = 0; k < ZZ; k += 32)
                acc = __builtin_amdgcn_mfma_f32_16x16x32_bf16(
                    *(const bf16x8*)(ap + k), *(const bf16x8*)(bp3 + k), acc, 0, 0, 0);
            int n = cg3 * 16 + col;
            float b = a.pzb[n];
            #pragma unroll
            for (int i = 0; i < 4; i++) {
                int m = mt * 16 + rq + i;
                a.pzbuf[m * HH + n] = (__bf16)fmaxf(acc[i] + b, 0.f);
            }
        }
        gbar(a.bar, p++, wg);

        // ---- P4: gi (3 gates) + gate math + h_new ----
        {
            int mt = mg4 * 4 + v;
            const __bf16* ap = a.pzbuf + (size_t)(mt * 16 + rr) * HH + ko;
            f32x4 acc[3] = {};
            #pragma unroll 2
            for (int k = 0; k < HH; k += 32) {
                bf16x8 af = *(const bf16x8*)(ap + k);
                #pragma unroll
                for (int g = 0; g < 3; g++)
                    acc[g] = __builtin_amdgcn_mfma_f32_16x16x32_bf16(
                        af, *(const bf16x8*)(bp4[g] + k), acc[g], 0, 0, 0);
            }
            int j = js4 * 16 + col;
            float br = a.bih[j], bz2 = a.bih[1024 + j], bn = a.bih[2048 + j];
            float cr = a.bhh[j], cz = a.bhh[1024 + j], cn = a.bhh[2048 + j];
            #pragma unroll
            for (int i = 0; i < 4; i++) {
                int m = mt * 16 + rq + i;
                int xb = a.x[m * SS + t];
                const float* gp = a.gipx + xb * 3072;
                float gir = acc[0][i] + gp[j] + br;
                float giz = acc[1][i] + gp[1024 + j] + bz2;
                float gin = acc[2][i] + gp[2048 + j] + bn;
                float ghr = a.gh[m * 3072 + j] + cr;
                float ghz = a.gh[m * 3072 + 1024 + j] + cz;
                float ghn = a.gh[m * 3072 + 2048 + j] + cn;
                float r = sigmoid_(gir + ghr);
                float zg = sigmoid_(giz + ghz);
                float nn = tanhf(gin + r * ghn);
                float hv = (1.f - zg) * nn + zg * hf[cur][m * HH + j];
                hf[nxt][m * HH + j] = hv;
                hb[nxt][m * HH + j] = (__bf16)hv;
            }
        }
        gbar(a.bar, p++, wg);
    }

    // kld partials -> kldbuf (per wave)
    {
        float s = kl;
        #pragma unroll
        for (int off = 1; off < 64; off <<= 1) s += __shfl_xor(s, off);
        if (lane == 0) a.kldbuf[gw] = s;
    }

    // ---- tail (final h is in buffer 0) ----
    // T1: tailhid = relu(h @ pri_w1^T + pb1), 256x1024, K=1024
    if (gw < 256) {
        int u = gw;
        int m0 = (u >> 5) * 32, n0 = (u & 31) * 32;
        f32x4 acc[2][2] = {};
        wgemm<2, 2>(hb[0] + m0 * HH, HH, 16 * HH, a.WA + (size_t)(1024 + n0) * HH, HH, 16 * HH, HH, acc);
        #pragma unroll
        for (int mt = 0; mt < 2; mt++)
            #pragma unroll
            for (int nt = 0; nt < 2; nt++) {
                int n = n0 + nt * 16 + col;
                float b = a.pb1[n];
                #pragma unroll
                for (int i = 0; i < 4; i++) {
                    int m = m0 + mt * 16 + rq + i;
                    a.tailhid[m * HH + n] = (__bf16)fmaxf(acc[mt][nt][i] + b, 0.f);
                }
            }
    }
    gbar(a.bar, p++, wg);
    // T2: pri logits -> z sample (eps[S]) -> zbuf
    if (v == 0) {
        int u = wg;
        int m0 = (u >> 4) * 16, z0 = (u & 15) * 16;
        f32x4 apv[1][1] = {};
        wgemm<1, 1>(a.tailhid + m0 * HH, HH, 16 * HH, a.W2 + (size_t)(256 + z0) * HH, HH, 16 * HH, HH, apv);
        int z = z0 + col;
        float bp = a.pb2[z];
        const float* epst = a.eps + (size_t)SS * BB * ZZ;
        #pragma unroll
        for (int i = 0; i < 4; i++) {
            int m = m0 + rq + i;
            float pri = apv[0][0][i] + bp;
            float ps = softplus_(pri);
            a.zbuf[m * ZZ + z] = (__bf16)(epst[m * ZZ + z] * ps + pri);
        }
    }
    gbar(a.bar, p++, wg);
    // T3: pz, 256x1024, K=256
    if (v == 0) {
        int u = wg;
        int m0 = (u >> 5) * 32, n0 = (u & 31) * 32;
        f32x4 acc[2][2] = {};
        wgemm<2, 2>(a.zbuf + m0 * ZZ, ZZ, 16 * ZZ, a.WPZ + (size_t)n0 * ZZ, ZZ, 16 * ZZ, ZZ, acc);
        #pragma unroll
        for (int mt = 0; mt < 2; mt++)
            #pragma unroll
            for (int nt = 0; nt < 2; nt++) {
                int n = n0 + nt * 16 + col;
                float b = a.pzb[n];
                #pragma unroll
                for (int i = 0; i < 4; i++) {
                    int m = m0 + mt * 16 + rq + i;
                    a.pzbuf[m * HH + n] = (__bf16)fmaxf(acc[mt][nt][i] + b, 0.f);
                }
            }
    }
    gbar(a.bar, p++, wg);
    // T4: dec = relu([pz|h] @ dec_w^T + b)
    if (gw < 256) {
        int u = gw;
        int m0 = (u >> 5) * 32, n0 = (u & 31) * 32;
        f32x4 acc[2][2] = {};
        wgemm<2, 2>(a.pzbuf + m0 * HH, HH, 16 * HH, a.WDEC + (size_t)n0 * 2048, 2048, 16 * 2048, HH, acc);
        wgemm<2, 2>(hb[0] + m0 * HH, HH, 16 * HH, a.WDEC + (size_t)n0 * 2048 + 1024, 2048, 16 * 2048, HH, acc);
        #pragma unroll
        for (int mt = 0; mt < 2; mt++)
            #pragma unroll
            for (int nt = 0; nt < 2; nt++) {
                int n = n0 + nt * 16 + col;
                float b = a.decb[n];
                #pragma unroll
                for (int i = 0; i < 4; i++) {
                    int m = m0 + mt * 16 + rq + i;
                    a.decbuf[m * HH + n] = (__bf16)fmaxf(acc[mt][nt][i] + b, 0.f);
                }
            }
    }
    gbar(a.bar, p++, wg);
    // T5: pred = dec @ act_w^T + act_b, 256x64
    if ((gw & 15) == 0) {
        int u = gw >> 4;
        int m0 = (u >> 2) * 16, n0 = (u & 3) * 16;
        f32x4 acc[1][1] = {};
        wgemm<1, 1>(a.decbuf + m0 * HH, HH, 16 * HH, a.WACT + (size_t)n0 * HH, HH, 16 * HH, HH, acc);
        int n = n0 + col;
        float b = a.actb[n];
        #pragma unroll
        for (int i = 0; i < 4; i++) {
            int m = m0 + rq + i;
            a.out[m * AA + n] = acc[0][0][i] + b;
        }
    }
    // kld final
    if (wg == 0 && v == 0) {
        float s = 0.f;
        for (int i = lane; i < 1024; i += 64) s += a.kldbuf[i];
        #pragma unroll
        for (int off = 1; off < 64; off <<= 1) s += __shfl_xor(s, off);
        if (lane == 0) a.out[BB * AA] = 0.5f * s;
    }
}

extern "C" void kernel_launch(void* const* d_in, const int* in_sizes, int n_in,
                              void* d_out, int out_size, void* d_ws, size_t ws_size,
                              hipStream_t stream) {
    const int*   x       = (const int*)d_in[0];
    const float* h0      = (const float*)d_in[1];
    const float* eps     = (const float*)d_in[2];
    const float* phi_x_w = (const float*)d_in[3];
    const float* phi_x_b = (const float*)d_in[4];
    const float* enc_w1  = (const float*)d_in[5];
    const float* enc_b1  = (const float*)d_in[6];
    const float* enc_w2  = (const float*)d_in[7];
    const float* enc_b2  = (const float*)d_in[8];
    const float* pri_w1  = (const float*)d_in[9];
    const float* pri_b1  = (const float*)d_in[10];
    const float* pri_w2  = (const float*)d_in[11];
    const float* pri_b2  = (const float*)d_in[12];
    const float* phi_z_w = (const float*)d_in[13];
    const float* phi_z_b = (const float*)d_in[14];
    const float* dec_w   = (const float*)d_in[15];
    const float* dec_b   = (const float*)d_in[16];
    const float* act_w   = (const float*)d_in[17];
    const float* act_b   = (const float*)d_in[18];
    const float* gru_wih = (const float*)d_in[19];
    const float* gru_whh = (const float*)d_in[20];
    const float* gru_bih = (const float*)d_in[21];
    const float* gru_bhh = (const float*)d_in[22];

    char* p = (char*)d_ws;
    auto alloc = [&](size_t bytes) { char* r = p; p += (bytes + 255) & ~(size_t)255; return r; };

    __bf16* WA    = (__bf16*)alloc(2048 * 1024 * 2);
    __bf16* W2    = (__bf16*)alloc(512 * 1024 * 2);
    __bf16* WPZ   = (__bf16*)alloc(1024 * 256 * 2);
    __bf16* WIH   = (__bf16*)alloc(3072 * 1024 * 2);
    __bf16* WHH   = (__bf16*)alloc(3072 * 1024 * 2);
    __bf16* WDEC  = (__bf16*)alloc(1024 * 2048 * 2);
    __bf16* WACT  = (__bf16*)alloc(64 * 1024 * 2);
    float*  px    = (float*)alloc(64 * 1024 * 4);
    float*  encpx = (float*)alloc(64 * 1024 * 4);
    float*  gipx  = (float*)alloc(64 * 3072 * 4);
    float*  hf0   = (float*)alloc(BB * HH * 4);
    float*  hf1   = (float*)alloc(BB * HH * 4);
    __bf16* hb0   = (__bf16*)alloc(BB * HH * 2);
    __bf16* hb1   = (__bf16*)alloc(BB * HH * 2);
    __bf16* hidcat = (__bf16*)alloc(BB * 2048 * 2);
    __bf16* zbuf   = (__bf16*)alloc(BB * ZZ * 2);
    __bf16* pzbuf  = (__bf16*)alloc(BB * HH * 2);
    __bf16* tailhid = (__bf16*)alloc(BB * HH * 2);
    __bf16* decbuf  = (__bf16*)alloc(BB * HH * 2);
    float*  gh     = (float*)alloc(BB * 3072 * 4);
    float*  kldbuf = (float*)alloc(1024 * 4);
    unsigned* bar  = (unsigned*)alloc(1280 * 4);

    auto pack = [&](const float* src, int src_ld, int off, __bf16* dst, int rows, int cols) {
        int total = rows * cols;
        k_pack<<<(total + 255) / 256, 256, 0, stream>>>(src, src_ld, off, dst, cols, total);
    };

    k_zerobar<<<1, 256, 0, stream>>>(bar);
    pack(enc_w1, 2048, 1024, WA, 1024, 1024);
    pack(pri_w1, 1024, 0, WA + 1024 * 1024, 1024, 1024);
    pack(enc_w2, 1024, 0, W2, 256, 1024);
    pack(pri_w2, 1024, 0, W2 + 256 * 1024, 256, 1024);
    pack(phi_z_w, 256, 0, WPZ, 1024, 256);
    pack(gru_wih, 2048, 1024, WIH, 3072, 1024);
    pack(gru_whh, 1024, 0, WHH, 3072, 1024);
    pack(dec_w, 2048, 0, WDEC, 1024, 2048);
    pack(act_w, 1024, 0, WACT, 64, 1024);
    pack(h0, 1024, 0, hb0, 256, 1024);
    k_copyf<<<(BB * HH + 255) / 256, 256, 0, stream>>>(h0, hf0, BB * HH);
    k_px<<<(64 * 1024) / 256, 256, 0, stream>>>(phi_x_w, phi_x_b, px);
    k_tables<<<1024, 256, 0, stream>>>(enc_w1, gru_wih, px, encpx, gipx);

    PArgs pa;
    pa.x = x; pa.eps = eps;
    pa.WA = WA; pa.W2 = W2; pa.WPZ = WPZ; pa.WIH = WIH; pa.WHH = WHH;
    pa.WDEC = WDEC; pa.WACT = WACT;
    pa.encpx = encpx; pa.gipx = gipx;
    pa.eb1 = enc_b1; pa.pb1 = pri_b1; pa.eb2 = enc_b2; pa.pb2 = pri_b2;
    pa.pzb = phi_z_b; pa.decb = dec_b; pa.actb = act_b;
    pa.bih = gru_bih; pa.bhh = gru_bhh;
    pa.hf0 = hf0; pa.hf1 = hf1; pa.hb0 = hb0; pa.hb1 = hb1;
    pa.hidcat = hidcat; pa.zbuf = zbuf; pa.pzbuf = pzbuf;
    pa.tailhid = tailhid; pa.decbuf = decbuf;
    pa.gh = gh; pa.kldbuf = kldbuf; pa.bar = bar;
    pa.out = (float*)d_out;

    k_persist<<<dim3(NWG), dim3(256), 0, stream>>>(pa);
}

// Round 4
// 29391.547 us; speedup vs baseline: 2.8005x; 2.8005x over previous
//
#include <hip/hip_runtime.h>

// CVRAE forward, XCD-local persistent version.
// B=256, S=512, A=64, H=1024, Z=256.
// Batch is split 32 rows per XCD; all per-step dataflow stays within one XCD's
// L2, so the per-step barrier is a cheap per-XCD flag barrier (relaxed stores,
// L2-resident polls) + L1 invalidate. Only 2 agent-scope global barriers total.

typedef float f32x4 __attribute__((ext_vector_type(4)));
typedef __bf16 bf16x8 __attribute__((ext_vector_type(8)));

#define BB 256
#define SS 512
#define HH 1024
#define ZZ 256
#define AA 64
#define NWG 256

__device__ __forceinline__ float softplus_(float x) {
    return (x > 15.f) ? x : log1pf(expf(x));
}
__device__ __forceinline__ float sigmoid_(float x) {
    return 1.f / (1.f + expf(-x));
}

// ---------------- global (agent) barrier — used ONLY twice ----------------
__device__ __forceinline__ void gbar(unsigned* bar, unsigned p, int wg) {
    __syncthreads();
    if (threadIdx.x == 0) {
        unsigned s = p & 7u;
        unsigned exp = (p >> 3) + 1u;
        unsigned* leaf = bar + (s * 8 + (wg >> 5)) * 16;
        unsigned* root = bar + (64 + s) * 16;
        unsigned* flag = bar + (72 + s) * 16;
        unsigned old = __hip_atomic_fetch_add(leaf, 1u, __ATOMIC_ACQ_REL, __HIP_MEMORY_SCOPE_AGENT);
        if (old == 32u * exp - 1u) {
            unsigned old2 = __hip_atomic_fetch_add(root, 1u, __ATOMIC_ACQ_REL, __HIP_MEMORY_SCOPE_AGENT);
            if (old2 == 8u * exp - 1u) {
                __hip_atomic_store(flag, exp, __ATOMIC_RELEASE, __HIP_MEMORY_SCOPE_AGENT);
            }
        }
        while (__hip_atomic_load(flag, __ATOMIC_ACQUIRE, __HIP_MEMORY_SCOPE_AGENT) < exp) {
            __builtin_amdgcn_s_sleep(2);
        }
    }
    __syncthreads();
}

// ---------------- per-XCD barrier ----------------
// flags[g*256 + rank]: each WG stores its token, polls its group's ngrp flags.
// No agent acquire/release: data lives in the shared per-XCD L2 (stores drained
// by __syncthreads before the flag store). L1 may be stale -> buffer_inv sc0.
__device__ __forceinline__ void xbar(unsigned* flags, int g, int rank, int ngrp,
                                     unsigned tok) {
    __syncthreads();   // all waves' stores drained to L2, exec sync
    if (threadIdx.x == 0)
        __hip_atomic_store(flags + g * 256 + rank, tok, __ATOMIC_RELAXED,
                           __HIP_MEMORY_SCOPE_AGENT);
    unsigned l = threadIdx.x & 63;
    unsigned* base = flags + g * 256;
    for (;;) {
        bool ok = true;
        for (int i = (int)l; i < ngrp; i += 64)
            ok &= (__hip_atomic_load(base + i, __ATOMIC_RELAXED,
                                     __HIP_MEMORY_SCOPE_AGENT) >= tok);
        if (__all(ok)) break;
        __builtin_amdgcn_s_sleep(2);
    }
    asm volatile("buffer_inv sc0" ::: "memory");   // invalidate per-CU L1 only
}

// ---------------- wave GEMM helper ----------------
template<int MT, int NT>
__device__ __forceinline__ void wgemm(const __bf16* __restrict__ A, int lda, int mstride,
                                      const __bf16* __restrict__ B, int ldb, int nstride,
                                      int K, f32x4 (&acc)[MT][NT]) {
    int lane = threadIdx.x & 63;
    int rr = lane & 15;
    int ko = (lane >> 4) * 8;
    const __bf16* ap = A + rr * lda + ko;
    const __bf16* bp = B + rr * ldb + ko;
    #pragma unroll 2
    for (int k = 0; k < K; k += 32) {
        bf16x8 af[MT], bfr[NT];
        #pragma unroll
        for (int mt = 0; mt < MT; mt++) af[mt] = *(const bf16x8*)(ap + mt * mstride + k);
        #pragma unroll
        for (int nt = 0; nt < NT; nt++) bfr[nt] = *(const bf16x8*)(bp + nt * nstride + k);
        #pragma unroll
        for (int mt = 0; mt < MT; mt++)
            #pragma unroll
            for (int nt = 0; nt < NT; nt++)
                acc[mt][nt] = __builtin_amdgcn_mfma_f32_16x16x32_bf16(af[mt], bfr[nt], acc[mt][nt], 0, 0, 0);
    }
}

// ---------------- prep kernels ----------------

__global__ void k_zeroctl(unsigned* bar, unsigned* flags, unsigned* cnt, float* kldacc) {
    for (int i = threadIdx.x; i < 1280; i += 256) bar[i] = 0u;
    for (int i = threadIdx.x; i < 2048; i += 256) flags[i] = 0u;
    if (threadIdx.x < 8) cnt[threadIdx.x] = 0u;
    if (threadIdx.x == 0) *kldacc = 0.f;
}

__global__ void k_pack(const float* __restrict__ src, int src_ld, int col_off,
                       __bf16* __restrict__ dst, int cols, int total) {
    int i = blockIdx.x * 256 + threadIdx.x;
    if (i >= total) return;
    int r = i / cols, c = i - r * cols;
    dst[i] = (__bf16)src[r * src_ld + col_off + c];
}

__global__ void k_copyf(const float* __restrict__ s, float* __restrict__ d, int n) {
    int i = blockIdx.x * 256 + threadIdx.x;
    if (i < n) d[i] = s[i];
}

__global__ void k_px(const float* __restrict__ phi_x_w, const float* __restrict__ phi_x_b,
                     float* __restrict__ px) {
    int i = blockIdx.x * 256 + threadIdx.x;  // 64*1024
    int a = i >> 10, hh = i & 1023;
    px[i] = fmaxf(phi_x_w[hh * AA + a] + phi_x_b[hh], 0.f);
}

__global__ __launch_bounds__(256) void k_tables(const float* __restrict__ enc_w1,
                                                const float* __restrict__ wih,
                                                const float* __restrict__ px,
                                                float* __restrict__ encpx,
                                                float* __restrict__ gipx) {
    __shared__ float spx[64][65];
    int tid = threadIdx.x;
    int cg = blockIdx.x * 4 + (tid >> 6);
    int a = tid & 63;
    const float* wrow = (cg < 1024) ? (enc_w1 + cg * 2048) : (wih + (cg - 1024) * 2048);
    float sum = 0.f;
    for (int k0 = 0; k0 < 1024; k0 += 64) {
        __syncthreads();
        for (int e = tid; e < 4096; e += 256)
            spx[e >> 6][e & 63] = px[((e >> 6) << 10) + k0 + (e & 63)];
        __syncthreads();
        #pragma unroll 8
        for (int kk = 0; kk < 64; kk++) sum += wrow[k0 + kk] * spx[a][kk];
    }
    if (cg < 1024) encpx[a * 1024 + cg] = sum;
    else gipx[a * 3072 + (cg - 1024)] = sum;
}

// ---------------- persistent kernel ----------------

struct PArgs {
    const int* x; const float* eps;
    const __bf16 *WA, *W2, *WPZ, *WIH, *WHH, *WDEC, *WACT;
    const float *encpx, *gipx;
    const float *eb1, *pb1, *eb2, *pb2, *pzb, *decb, *actb, *bih, *bhh;
    float *hf0, *hf1; __bf16 *hb0, *hb1;
    __bf16 *hidcat, *zbuf, *pzbuf, *tailhid, *decbuf;
    float *gh; float *kldacc; unsigned *bar, *flags, *cnt;
    float* out;
};

__global__ __launch_bounds__(256) void k_persist(PArgs a) {
    int wg = blockIdx.x;
    int tid = threadIdx.x;
    int v = tid >> 6;                // wave in WG
    int lane = tid & 63;
    int rr = lane & 15;              // fragment row
    int ko = (lane >> 4) * 8;        // fragment k-offset
    int col = lane & 15, rq = (lane >> 4) * 4;
    float kl = 0.f;
    float* hf[2] = {a.hf0, a.hf1};
    __bf16* hb[2] = {a.hb0, a.hb1};

    __shared__ float lds2[4][2][256];   // P2 K-split partials
    __shared__ int sh_g, sh_rank, sh_ngrp;
    __shared__ float sh_kl[4];

    // ---- XCD registration (mapping-robust grouping) ----
    if (tid == 0) {
        unsigned xcc = __builtin_amdgcn_s_getreg((31 << 11) | (0 << 6) | 20) & 7u;
        sh_g = (int)xcc;
        sh_rank = (int)atomicAdd(a.cnt + xcc, 1u);
    }
    __syncthreads();
    int g = sh_g, rank = sh_rank;
    gbar(a.bar, 0, wg);                 // counts final + cache sync
    if (tid == 0)
        sh_ngrp = (int)__hip_atomic_load(a.cnt + g, __ATOMIC_RELAXED,
                                         __HIP_MEMORY_SCOPE_AGENT);
    __syncthreads();
    int ngrp = sh_ngrp;
    int base_m = g * 32;                // this XCD's 32 batch rows

    unsigned tok = 1;

    for (int t = 0; t < SS; t++) {
        int cur = t & 1, nxt = cur ^ 1;

        // ---- P1: hidcat (cols 0..2047) + gh (cols 2048..5119), K=1024 ----
        for (int r = rank; r < 32; r += ngrp) {
            int mt = v >> 1;                     // 0/1
            int nt0 = r * 10 + (v & 1) * 5;      // 5 n-tiles of 16
            const __bf16* ap = hb[cur] + (size_t)(base_m + mt * 16 + rr) * HH + ko;
            const __bf16* bp[5];
            #pragma unroll
            for (int j = 0; j < 5; j++) {
                int n = (nt0 + j) * 16 + rr;
                bp[j] = ((n < 2048) ? (a.WA + (size_t)n * HH)
                                    : (a.WHH + (size_t)(n - 2048) * HH)) + ko;
            }
            f32x4 acc[5] = {};
            #pragma unroll 2
            for (int k = 0; k < HH; k += 32) {
                bf16x8 af = *(const bf16x8*)(ap + k);
                #pragma unroll
                for (int j = 0; j < 5; j++)
                    acc[j] = __builtin_amdgcn_mfma_f32_16x16x32_bf16(
                        af, *(const bf16x8*)(bp[j] + k), acc[j], 0, 0, 0);
            }
            int xb[4];
            #pragma unroll
            for (int i = 0; i < 4; i++)
                xb[i] = a.x[(base_m + mt * 16 + rq + i) * SS + t];
            #pragma unroll
            for (int j = 0; j < 5; j++) {
                int c0 = (nt0 + j) * 16 + col;
                if (c0 < 1024) {
                    float bias = a.eb1[c0];
                    #pragma unroll
                    for (int i = 0; i < 4; i++) {
                        int m = base_m + mt * 16 + rq + i;
                        float val = acc[j][i] + bias + a.encpx[xb[i] * 1024 + c0];
                        a.hidcat[m * 2048 + c0] = (__bf16)fmaxf(val, 0.f);
                    }
                } else if (c0 < 2048) {
                    float bias = a.pb1[c0 - 1024];
                    #pragma unroll
                    for (int i = 0; i < 4; i++) {
                        int m = base_m + mt * 16 + rq + i;
                        a.hidcat[m * 2048 + c0] = (__bf16)fmaxf(acc[j][i] + bias, 0.f);
                    }
                } else {
                    int gc = c0 - 2048;
                    #pragma unroll
                    for (int i = 0; i < 4; i++) {
                        int m = base_m + mt * 16 + rq + i;
                        a.gh[m * 3072 + gc] = acc[j][i];
                    }
                }
            }
        }
        xbar(a.flags, g, rank, ngrp, tok++);

        // ---- P2: enc/pri logits (K split over 4 waves), kld, z sample ----
        for (int r = rank; r < 32; r += ngrp) {
            int mtl = r >> 4, zsl = r & 15;
            const __bf16* ae_p = a.hidcat + (size_t)(base_m + mtl * 16 + rr) * 2048 + v * 256 + ko;
            const __bf16* ap_p = ae_p + 1024;
            const __bf16* be_p = a.W2 + (size_t)(zsl * 16 + rr) * HH + v * 256 + ko;
            const __bf16* bp_p = a.W2 + (size_t)(256 + zsl * 16 + rr) * HH + v * 256 + ko;
            f32x4 ae = {0.f,0.f,0.f,0.f}, av = {0.f,0.f,0.f,0.f};
            #pragma unroll
            for (int k = 0; k < 256; k += 32) {
                ae = __builtin_amdgcn_mfma_f32_16x16x32_bf16(
                    *(const bf16x8*)(ae_p + k), *(const bf16x8*)(be_p + k), ae, 0, 0, 0);
                av = __builtin_amdgcn_mfma_f32_16x16x32_bf16(
                    *(const bf16x8*)(ap_p + k), *(const bf16x8*)(bp_p + k), av, 0, 0, 0);
            }
            #pragma unroll
            for (int i = 0; i < 4; i++) {
                int idx = (rq + i) * 16 + col;
                lds2[v][0][idx] = ae[i];
                lds2[v][1][idx] = av[i];
            }
            __syncthreads();
            {
                float e = lds2[0][0][tid] + lds2[1][0][tid] + lds2[2][0][tid] + lds2[3][0][tid];
                float pv = lds2[0][1][tid] + lds2[1][1][tid] + lds2[2][1][tid] + lds2[3][1][tid];
                int m = base_m + mtl * 16 + (tid >> 4);
                int z = zsl * 16 + (tid & 15);
                float enc = e + a.eb2[z];
                float pri = pv + a.pb2[z];
                float es = softplus_(enc), ps = softplus_(pri);
                float d = enc - pri;
                kl += 2.f * (logf(ps) - logf(es)) + (es * es + d * d) / (ps * ps) - 1.f;
                const float* epst = a.eps + (size_t)t * BB * ZZ;
                a.zbuf[m * ZZ + z] = (__bf16)(epst[m * ZZ + z] * es + enc);
            }
            __syncthreads();
        }
        xbar(a.flags, g, rank, ngrp, tok++);

        // ---- P3: pz = relu(z @ phi_z_w^T + b), K=256 ----
        for (int r = rank; r < 32; r += ngrp) {
            int mt = v >> 1;
            int nt = r * 2 + (v & 1);
            const __bf16* ap = a.zbuf + (size_t)(base_m + mt * 16 + rr) * ZZ + ko;
            const __bf16* bp = a.WPZ + (size_t)(nt * 16 + rr) * ZZ + ko;
            f32x4 acc = {0.f,0.f,0.f,0.f};
            #pragma unroll
            for (int k = 0; k < ZZ; k += 32)
                acc = __builtin_amdgcn_mfma_f32_16x16x32_bf16(
                    *(const bf16x8*)(ap + k), *(const bf16x8*)(bp + k), acc, 0, 0, 0);
            int n = nt * 16 + col;
            float b = a.pzb[n];
            #pragma unroll
            for (int i = 0; i < 4; i++) {
                int m = base_m + mt * 16 + rq + i;
                a.pzbuf[m * HH + n] = (__bf16)fmaxf(acc[i] + b, 0.f);
            }
        }
        xbar(a.flags, g, rank, ngrp, tok++);

        // ---- P4: gi (3 gates, same j-slice) + gate math + h_new, K=1024 ----
        for (int r = rank; r < 32; r += ngrp) {
            int mt = v >> 1;
            int jt = r * 2 + (v & 1);            // j-tile [0,64)
            const __bf16* ap = a.pzbuf + (size_t)(base_m + mt * 16 + rr) * HH + ko;
            const __bf16* bp0 = a.WIH + (size_t)(jt * 16 + rr) * HH + ko;
            const __bf16* bp1g = bp0 + (size_t)1024 * HH;
            const __bf16* bp2g = bp0 + (size_t)2048 * HH;
            f32x4 acc[3] = {};
            #pragma unroll 2
            for (int k = 0; k < HH; k += 32) {
                bf16x8 af = *(const bf16x8*)(ap + k);
                acc[0] = __builtin_amdgcn_mfma_f32_16x16x32_bf16(af, *(const bf16x8*)(bp0 + k), acc[0], 0, 0, 0);
                acc[1] = __builtin_amdgcn_mfma_f32_16x16x32_bf16(af, *(const bf16x8*)(bp1g + k), acc[1], 0, 0, 0);
                acc[2] = __builtin_amdgcn_mfma_f32_16x16x32_bf16(af, *(const bf16x8*)(bp2g + k), acc[2], 0, 0, 0);
            }
            int j = jt * 16 + col;
            float br = a.bih[j], bz2 = a.bih[1024 + j], bn = a.bih[2048 + j];
            float cr = a.bhh[j], cz = a.bhh[1024 + j], cn = a.bhh[2048 + j];
            #pragma unroll
            for (int i = 0; i < 4; i++) {
                int m = base_m + mt * 16 + rq + i;
                int xb = a.x[m * SS + t];
                const float* gp = a.gipx + xb * 3072;
                float gir = acc[0][i] + gp[j] + br;
                float giz = acc[1][i] + gp[1024 + j] + bz2;
                float gin = acc[2][i] + gp[2048 + j] + bn;
                float ghr = a.gh[m * 3072 + j] + cr;
                float ghz = a.gh[m * 3072 + 1024 + j] + cz;
                float ghn = a.gh[m * 3072 + 2048 + j] + cn;
                float rg = sigmoid_(gir + ghr);
                float zg = sigmoid_(giz + ghz);
                float nn = tanhf(gin + rg * ghn);
                float hv = (1.f - zg) * nn + zg * hf[cur][m * HH + j];
                hf[nxt][m * HH + j] = hv;
                hb[nxt][m * HH + j] = (__bf16)hv;
            }
        }
        xbar(a.flags, g, rank, ngrp, tok++);
    }

    // ---- tail (final h in buffer 0, per-XCD rows) ----
    // T1: tailhid = relu(h @ pri_w1^T + pb1), K=1024
    for (int r = rank; r < 32; r += ngrp) {
        int mt = v >> 1, nt = r * 2 + (v & 1);
        f32x4 acc[1][1] = {};
        wgemm<1, 1>(hb[0] + (size_t)(base_m + mt * 16) * HH, HH, 0,
                    a.WA + (size_t)(1024 + nt * 16) * HH, HH, 0, HH, acc);
        int n = nt * 16 + col;
        float b = a.pb1[n];
        #pragma unroll
        for (int i = 0; i < 4; i++) {
            int m = base_m + mt * 16 + rq + i;
            a.tailhid[m * HH + n] = (__bf16)fmaxf(acc[0][0][i] + b, 0.f);
        }
    }
    xbar(a.flags, g, rank, ngrp, tok++);
    // T2: pri logits -> z sample (eps[S])
    if (v == 0) {
        for (int r = rank; r < 32; r += ngrp) {
            int mtl = r >> 4, zt = r & 15;
            f32x4 apv[1][1] = {};
            wgemm<1, 1>(a.tailhid + (size_t)(base_m + mtl * 16) * HH, HH, 0,
                        a.W2 + (size_t)(256 + zt * 16) * HH, HH, 0, HH, apv);
            int z = zt * 16 + col;
            float bp = a.pb2[z];
            const float* epst = a.eps + (size_t)SS * BB * ZZ;
            #pragma unroll
            for (int i = 0; i < 4; i++) {
                int m = base_m + mtl * 16 + rq + i;
                float pri = apv[0][0][i] + bp;
                float ps = softplus_(pri);
                a.zbuf[m * ZZ + z] = (__bf16)(epst[m * ZZ + z] * ps + pri);
            }
        }
    }
    xbar(a.flags, g, rank, ngrp, tok++);
    // T3: pz, K=256
    for (int r = rank; r < 32; r += ngrp) {
        int mt = v >> 1, nt = r * 2 + (v & 1);
        f32x4 acc[1][1] = {};
        wgemm<1, 1>(a.zbuf + (size_t)(base_m + mt * 16) * ZZ, ZZ, 0,
                    a.WPZ + (size_t)(nt * 16) * ZZ, ZZ, 0, ZZ, acc);
        int n = nt * 16 + col;
        float b = a.pzb[n];
        #pragma unroll
        for (int i = 0; i < 4; i++) {
            int m = base_m + mt * 16 + rq + i;
            a.pzbuf[m * HH + n] = (__bf16)fmaxf(acc[0][0][i] + b, 0.f);
        }
    }
    xbar(a.flags, g, rank, ngrp, tok++);
    // T4: dec = relu([pz|h] @ dec_w^T + b), K=2048 in two halves
    for (int r = rank; r < 32; r += ngrp) {
        int mt = v >> 1, nt = r * 2 + (v & 1);
        f32x4 acc[1][1] = {};
        wgemm<1, 1>(a.pzbuf + (size_t)(base_m + mt * 16) * HH, HH, 0,
                    a.WDEC + (size_t)(nt * 16) * 2048, 2048, 0, HH, acc);
        wgemm<1, 1>(hb[0] + (size_t)(base_m + mt * 16) * HH, HH, 0,
                    a.WDEC + (size_t)(nt * 16) * 2048 + 1024, 2048, 0, HH, acc);
        int n = nt * 16 + col;
        float b = a.decb[n];
        #pragma unroll
        for (int i = 0; i < 4; i++) {
            int m = base_m + mt * 16 + rq + i;
            a.decbuf[m * HH + n] = (__bf16)fmaxf(acc[0][0][i] + b, 0.f);
        }
    }
    xbar(a.flags, g, rank, ngrp, tok++);
    // T5: pred = dec @ act_w^T + act_b (only slices 0..7)
    if (v == 0) {
        for (int r = rank; r < 32; r += ngrp) {
            if (r >= 8) continue;
            int mt = r >> 2, nt = r & 3;
            f32x4 acc[1][1] = {};
            wgemm<1, 1>(a.decbuf + (size_t)(base_m + mt * 16) * HH, HH, 0,
                        a.WACT + (size_t)(nt * 16) * HH, HH, 0, HH, acc);
            int n = nt * 16 + col;
            float b = a.actb[n];
            #pragma unroll
            for (int i = 0; i < 4; i++) {
                int m = base_m + mt * 16 + rq + i;
                a.out[m * AA + n] = acc[0][0][i] + b;
            }
        }
    }

    // ---- kld reduce: wave -> WG -> device atomic ----
    {
        float s = kl;
        #pragma unroll
        for (int off = 1; off < 64; off <<= 1) s += __shfl_xor(s, off);
        if (lane == 0) sh_kl[v] = s;
        __syncthreads();
        if (tid == 0) {
            float ws = sh_kl[0] + sh_kl[1] + sh_kl[2] + sh_kl[3];
            atomicAdd(a.kldacc, ws);
        }
    }
    gbar(a.bar, 1, wg);
    if (wg == 0 && tid == 0) {
        float s = __hip_atomic_load(a.kldacc, __ATOMIC_ACQUIRE, __HIP_MEMORY_SCOPE_AGENT);
        a.out[BB * AA] = 0.5f * s;
    }
}

extern "C" void kernel_launch(void* const* d_in, const int* in_sizes, int n_in,
                              void* d_out, int out_size, void* d_ws, size_t ws_size,
                              hipStream_t stream) {
    const int*   x       = (const int*)d_in[0];
    const float* h0      = (const float*)d_in[1];
    const float* eps     = (const float*)d_in[2];
    const float* phi_x_w = (const float*)d_in[3];
    const float* phi_x_b = (const float*)d_in[4];
    const float* enc_w1  = (const float*)d_in[5];
    const float* enc_b1  = (const float*)d_in[6];
    const float* enc_w2  = (const float*)d_in[7];
    const float* enc_b2  = (const float*)d_in[8];
    const float* pri_w1  = (const float*)d_in[9];
    const float* pri_b1  = (const float*)d_in[10];
    const float* pri_w2  = (const float*)d_in[11];
    const float* pri_b2  = (const float*)d_in[12];
    const float* phi_z_w = (const float*)d_in[13];
    const float* phi_z_b = (const float*)d_in[14];
    const float* dec_w   = (const float*)d_in[15];
    const float* dec_b   = (const float*)d_in[16];
    const float* act_w   = (const float*)d_in[17];
    const float* act_b   = (const float*)d_in[18];
    const float* gru_wih = (const float*)d_in[19];
    const float* gru_whh = (const float*)d_in[20];
    const float* gru_bih = (const float*)d_in[21];
    const float* gru_bhh = (const float*)d_in[22];

    char* p = (char*)d_ws;
    auto alloc = [&](size_t bytes) { char* r = p; p += (bytes + 255) & ~(size_t)255; return r; };

    __bf16* WA    = (__bf16*)alloc(2048 * 1024 * 2);
    __bf16* W2    = (__bf16*)alloc(512 * 1024 * 2);
    __bf16* WPZ   = (__bf16*)alloc(1024 * 256 * 2);
    __bf16* WIH   = (__bf16*)alloc(3072 * 1024 * 2);
    __bf16* WHH   = (__bf16*)alloc(3072 * 1024 * 2);
    __bf16* WDEC  = (__bf16*)alloc(1024 * 2048 * 2);
    __bf16* WACT  = (__bf16*)alloc(64 * 1024 * 2);
    float*  px    = (float*)alloc(64 * 1024 * 4);
    float*  encpx = (float*)alloc(64 * 1024 * 4);
    float*  gipx  = (float*)alloc(64 * 3072 * 4);
    float*  hf0   = (float*)alloc(BB * HH * 4);
    float*  hf1   = (float*)alloc(BB * HH * 4);
    __bf16* hb0   = (__bf16*)alloc(BB * HH * 2);
    __bf16* hb1   = (__bf16*)alloc(BB * HH * 2);
    __bf16* hidcat = (__bf16*)alloc(BB * 2048 * 2);
    __bf16* zbuf   = (__bf16*)alloc(BB * ZZ * 2);
    __bf16* pzbuf  = (__bf16*)alloc(BB * HH * 2);
    __bf16* tailhid = (__bf16*)alloc(BB * HH * 2);
    __bf16* decbuf  = (__bf16*)alloc(BB * HH * 2);
    float*  gh     = (float*)alloc(BB * 3072 * 4);
    unsigned* bar  = (unsigned*)alloc(1280 * 4);
    unsigned* flags = (unsigned*)alloc(2048 * 4);
    unsigned* cnt  = (unsigned*)alloc(64 * 4);
    float*  kldacc = (float*)alloc(256);

    auto pack = [&](const float* src, int src_ld, int off, __bf16* dst, int rows, int cols) {
        int total = rows * cols;
        k_pack<<<(total + 255) / 256, 256, 0, stream>>>(src, src_ld, off, dst, cols, total);
    };

    k_zeroctl<<<1, 256, 0, stream>>>(bar, flags, cnt, kldacc);
    pack(enc_w1, 2048, 1024, WA, 1024, 1024);
    pack(pri_w1, 1024, 0, WA + 1024 * 1024, 1024, 1024);
    pack(enc_w2, 1024, 0, W2, 256, 1024);
    pack(pri_w2, 1024, 0, W2 + 256 * 1024, 256, 1024);
    pack(phi_z_w, 256, 0, WPZ, 1024, 256);
    pack(gru_wih, 2048, 1024, WIH, 3072, 1024);
    pack(gru_whh, 1024, 0, WHH, 3072, 1024);
    pack(dec_w, 2048, 0, WDEC, 1024, 2048);
    pack(act_w, 1024, 0, WACT, 64, 1024);
    pack(h0, 1024, 0, hb0, 256, 1024);
    k_copyf<<<(BB * HH + 255) / 256, 256, 0, stream>>>(h0, hf0, BB * HH);
    k_px<<<(64 * 1024) / 256, 256, 0, stream>>>(phi_x_w, phi_x_b, px);
    k_tables<<<1024, 256, 0, stream>>>(enc_w1, gru_wih, px, encpx, gipx);

    PArgs pa;
    pa.x = x; pa.eps = eps;
    pa.WA = WA; pa.W2 = W2; pa.WPZ = WPZ; pa.WIH = WIH; pa.WHH = WHH;
    pa.WDEC = WDEC; pa.WACT = WACT;
    pa.encpx = encpx; pa.gipx = gipx;
    pa.eb1 = enc_b1; pa.pb1 = pri_b1; pa.eb2 = enc_b2; pa.pb2 = pri_b2;
    pa.pzb = phi_z_b; pa.decb = dec_b; pa.actb = act_b;
    pa.bih = gru_bih; pa.bhh = gru_bhh;
    pa.hf0 = hf0; pa.hf1 = hf1; pa.hb0 = hb0; pa.hb1 = hb1;
    pa.hidcat = hidcat; pa.zbuf = zbuf; pa.pzbuf = pzbuf;
    pa.tailhid = tailhid; pa.decbuf = decbuf;
    pa.gh = gh; pa.kldacc = kldacc;
    pa.bar = bar; pa.flags = flags; pa.cnt = cnt;
    pa.out = (float*)d_out;

    k_persist<<<dim3(NWG), dim3(256), 0, stream>>>(pa);
}